// Round 1
// baseline (202.849 us; speedup 1.0000x reference)
//
#include <hip/hip_runtime.h>

// Problem constants: B=2, N=96, D=64, H=4, DK=16
#define N_ROWS 9216       // 96*96 edges per batch
#define T_ROWS 18432      // B * N_ROWS

// ---------------------------------------------------------------------------
// Kernel 1: fused 4-way projection  lk/rk/lv/rv = state @ W^T + b
// grid = T_ROWS/16 = 1152 blocks, 256 threads.
// Weights staged transposed in LDS (swt[k][c] = w[c*64+k]) with +1 pad so
// lane-consecutive c reads are conflict-free.
// ---------------------------------------------------------------------------
__global__ __launch_bounds__(256) void proj4_kernel(
    const float* __restrict__ state,
    const float* __restrict__ w_lk, const float* __restrict__ b_lk,
    const float* __restrict__ w_rk, const float* __restrict__ b_rk,
    const float* __restrict__ w_lv, const float* __restrict__ b_lv,
    const float* __restrict__ w_rv, const float* __restrict__ b_rv,
    float* __restrict__ lk, float* __restrict__ rk,
    float* __restrict__ lv, float* __restrict__ rv)
{
    __shared__ float swt[4][64][65];   // [mat][k][c], padded
    __shared__ float sbias[4][64];
    __shared__ float srow[16][64];
    const int t = threadIdx.x;

    const float* wsrc[4] = {w_lk, w_rk, w_lv, w_rv};
    const float* bsrc[4] = {b_lk, b_rk, b_lv, b_rv};
#pragma unroll
    for (int m = 0; m < 4; ++m) {
        for (int i = t; i < 4096; i += 256)
            swt[m][i & 63][i >> 6] = wsrc[m][i];   // stride-65 writes: conflict-free
        if (t < 64) sbias[m][t] = bsrc[m][t];
    }
    const int row0 = blockIdx.x * 16;
    for (int i = t; i < 1024; i += 256)
        srow[i >> 6][i & 63] = state[row0 * 64 + i];
    __syncthreads();

    const int c  = t & 63;      // output column
    const int rg = t >> 6;      // row group 0..3 -> rows rg*4 .. rg*4+3
    float acc[4][4];
#pragma unroll
    for (int m = 0; m < 4; ++m)
#pragma unroll
        for (int rr = 0; rr < 4; ++rr)
            acc[m][rr] = sbias[m][c];

    for (int k = 0; k < 64; ++k) {
        const float s0 = srow[rg * 4 + 0][k];
        const float s1 = srow[rg * 4 + 1][k];
        const float s2 = srow[rg * 4 + 2][k];
        const float s3 = srow[rg * 4 + 3][k];
#pragma unroll
        for (int m = 0; m < 4; ++m) {
            const float w = swt[m][k][c];
            acc[m][0] = fmaf(s0, w, acc[m][0]);
            acc[m][1] = fmaf(s1, w, acc[m][1]);
            acc[m][2] = fmaf(s2, w, acc[m][2]);
            acc[m][3] = fmaf(s3, w, acc[m][3]);
        }
    }
    float* outs[4] = {lk, rk, lv, rv};
#pragma unroll
    for (int m = 0; m < 4; ++m)
#pragma unroll
        for (int rr = 0; rr < 4; ++rr)
            outs[m][(row0 + rg * 4 + rr) * 64 + c] = acc[m][rr];
}

// ---------------------------------------------------------------------------
// Kernel 2: edge attention. One block per (b, x, h): 768 blocks, 384 threads.
// LDS: lk/lv x-slices (96x16 each) + full S[a][y] score tile (96x96).
//   phase 1: S[a][y] = 0.25 * dot16(lk[x,a,h,:], rk[a,y,h,:])
//   phase 2: softmax over a (per column y)
//   phase 3: out[y,d] = sum_a att[a][y] * lv[a][d] * rv[a,y,d]
// ---------------------------------------------------------------------------
__global__ __launch_bounds__(384) void edge_attn_kernel(
    const float* __restrict__ lk, const float* __restrict__ rk,
    const float* __restrict__ lv, const float* __restrict__ rv,
    float* __restrict__ xb)
{
    __shared__ float lks[96][16];
    __shared__ float lvs[96][16];
    __shared__ float S[96][96];   // S[a][y]
    const int t   = threadIdx.x;
    const int bid = blockIdx.x;          // ((b*4 + h)*96 + x): x fastest -> (b,h) L2 locality
    const int x = bid % 96;
    const int h = (bid / 96) & 3;
    const int b = bid / 384;
    const int baseB = b * N_ROWS * 64;
    const int hoff  = h * 16;

    {   // stage lk/lv slices: 384 threads cover 96 rows x 4 float4-quads exactly
        const int a = t >> 2, q = t & 3;
        const int idx = baseB + (x * 96 + a) * 64 + hoff + q * 4;
        *(float4*)&lks[a][q * 4] = *(const float4*)(lk + idx);
        *(float4*)&lvs[a][q * 4] = *(const float4*)(lv + idx);
    }
    __syncthreads();

    // phase 1: 9216 (a,y) pairs, 24 per thread
    for (int p = t; p < 9216; p += 384) {
        const int a = p / 96, y = p - a * 96;
        const float4* rp = (const float4*)(rk + baseB + (a * 96 + y) * 64 + hoff);
        const float4 r0 = rp[0], r1 = rp[1], r2 = rp[2], r3 = rp[3];
        const float4* lp = (const float4*)lks[a];
        const float4 l0 = lp[0], l1 = lp[1], l2 = lp[2], l3 = lp[3];
        float acc = r0.x * l0.x + r0.y * l0.y + r0.z * l0.z + r0.w * l0.w
                  + r1.x * l1.x + r1.y * l1.y + r1.z * l1.z + r1.w * l1.w
                  + r2.x * l2.x + r2.y * l2.y + r2.z * l2.z + r2.w * l2.w
                  + r3.x * l3.x + r3.y * l3.y + r3.z * l3.z + r3.w * l3.w;
        S[a][y] = acc * 0.25f;   // 1/sqrt(16)
    }
    __syncthreads();

    // phase 2: softmax over a, one thread per column y
    if (t < 96) {
        const int y = t;
        float mx = -1e30f;
        for (int a = 0; a < 96; ++a) mx = fmaxf(mx, S[a][y]);
        float sum = 0.0f;
        for (int a = 0; a < 96; ++a) {
            const float e = __expf(S[a][y] - mx);
            S[a][y] = e;
            sum += e;
        }
        const float inv = 1.0f / sum;
        for (int a = 0; a < 96; ++a) S[a][y] *= inv;
    }
    __syncthreads();

    // phase 3: 96 y * 4 quads = 384 items, one per thread
    {
        const int y = t >> 2, q = t & 3;
        float4 acc = {0.f, 0.f, 0.f, 0.f};
        for (int a = 0; a < 96; ++a) {
            const float att = S[a][y];
            const float4 lv4 = *(const float4*)&lvs[a][q * 4];
            const float4 rv4 = *(const float4*)(rv + baseB + (a * 96 + y) * 64 + hoff + q * 4);
            acc.x = fmaf(att * lv4.x, rv4.x, acc.x);
            acc.y = fmaf(att * lv4.y, rv4.y, acc.y);
            acc.z = fmaf(att * lv4.z, rv4.z, acc.z);
            acc.w = fmaf(att * lv4.w, rv4.w, acc.w);
        }
        *(float4*)(xb + baseB + (x * 96 + y) * 64 + hoff + q * 4) = acc;
    }
}

// ---------------------------------------------------------------------------
// Kernel 3: output projection  out = xb @ w_out^T + b_out
// ---------------------------------------------------------------------------
__global__ __launch_bounds__(256) void out_proj_kernel(
    const float* __restrict__ xb, const float* __restrict__ w_out,
    const float* __restrict__ b_out, float* __restrict__ out)
{
    __shared__ float swt[64][65];
    __shared__ float sbias[64];
    __shared__ float srow[16][64];
    const int t = threadIdx.x;
    for (int i = t; i < 4096; i += 256)
        swt[i & 63][i >> 6] = w_out[i];
    if (t < 64) sbias[t] = b_out[t];
    const int row0 = blockIdx.x * 16;
    for (int i = t; i < 1024; i += 256)
        srow[i >> 6][i & 63] = xb[row0 * 64 + i];
    __syncthreads();

    const int c = t & 63, rg = t >> 6;
    float acc[4];
#pragma unroll
    for (int rr = 0; rr < 4; ++rr) acc[rr] = sbias[c];
    for (int k = 0; k < 64; ++k) {
        const float w = swt[k][c];
#pragma unroll
        for (int rr = 0; rr < 4; ++rr)
            acc[rr] = fmaf(srow[rg * 4 + rr][k], w, acc[rr]);
    }
#pragma unroll
    for (int rr = 0; rr < 4; ++rr)
        out[(row0 + rg * 4 + rr) * 64 + c] = acc[rr];
}

extern "C" void kernel_launch(void* const* d_in, const int* in_sizes, int n_in,
                              void* d_out, int out_size, void* d_ws, size_t ws_size,
                              hipStream_t stream)
{
    const float* state = (const float*)d_in[0];
    const float* w_lk  = (const float*)d_in[1];
    const float* b_lk  = (const float*)d_in[2];
    const float* w_rk  = (const float*)d_in[3];
    const float* b_rk  = (const float*)d_in[4];
    const float* w_lv  = (const float*)d_in[5];
    const float* b_lv  = (const float*)d_in[6];
    const float* w_rv  = (const float*)d_in[7];
    const float* b_rv  = (const float*)d_in[8];
    const float* w_out = (const float*)d_in[9];
    const float* b_out = (const float*)d_in[10];
    float* out = (float*)d_out;

    const int TENS = T_ROWS * 64;   // 1179648 elements per projected tensor
    float* ws = (float*)d_ws;
    float* lk = ws;
    float* rk = ws + (size_t)TENS;
    float* lv = ws + (size_t)2 * TENS;
    float* rv = ws + (size_t)3 * TENS;
    float* xb = ws + (size_t)4 * TENS;

    proj4_kernel<<<T_ROWS / 16, 256, 0, stream>>>(
        state, w_lk, b_lk, w_rk, b_rk, w_lv, b_lv, w_rv, b_rv, lk, rk, lv, rv);
    edge_attn_kernel<<<2 * 4 * 96, 384, 0, stream>>>(lk, rk, lv, rv, xb);
    out_proj_kernel<<<T_ROWS / 16, 256, 0, stream>>>(xb, w_out, b_out, out);
}

// Round 2
// 147.649 us; speedup vs baseline: 1.3739x; 1.3739x over previous
//
#include <hip/hip_runtime.h>

// B=2, N=96, D=64, H=4, DK=16
#define NB     96
#define ELEM_B 589824    // 9216*64 floats per batch per tensor
#define TENS   1179648   // 2*ELEM_B floats per projected tensor
#define T_ROWS 18432     // total rows

// ---------------------------------------------------------------------------
// Generic 32-row x 64-col projection tile: dst = src @ W^T + b
// 256 threads: c = t&63 (col), rg = t>>6 (8 rows each). Weights staged with
// pitch 68 (16B aligned; 8 distinct addrs/bank = b128 baseline, no conflict).
// ---------------------------------------------------------------------------
__device__ __forceinline__ void proj_tile(
    const float* __restrict__ src, const float* __restrict__ w,
    const float* __restrict__ bias, float* __restrict__ dst,
    int row0, int t, float* sw, float* srow, float* sb)
{
#pragma unroll
    for (int j = 0; j < 4; ++j) {           // 1024 float4 slots of W
        const int s = t + j * 256;
        const int c = s >> 4, k4 = s & 15;
        *(float4*)&sw[c * 68 + k4 * 4] = *(const float4*)(w + s * 4);
    }
#pragma unroll
    for (int j = 0; j < 2; ++j) {           // 512 float4 slots of src rows
        const int s = t + j * 256;
        *(float4*)&srow[s * 4] = *(const float4*)(src + row0 * 64 + s * 4);
    }
    if (t < 64) sb[t] = bias[t];
    __syncthreads();

    const int c = t & 63, rg = t >> 6;
    float acc[8];
#pragma unroll
    for (int r = 0; r < 8; ++r) acc[r] = sb[c];
#pragma unroll
    for (int k4 = 0; k4 < 16; ++k4) {
        const float4 w4 = *(const float4*)&sw[c * 68 + k4 * 4];
#pragma unroll
        for (int r = 0; r < 8; ++r) {
            const float4 s4 = *(const float4*)&srow[(rg * 8 + r) * 64 + k4 * 4];
            acc[r] = fmaf(s4.x, w4.x, acc[r]);
            acc[r] = fmaf(s4.y, w4.y, acc[r]);
            acc[r] = fmaf(s4.z, w4.z, acc[r]);
            acc[r] = fmaf(s4.w, w4.w, acc[r]);
        }
    }
#pragma unroll
    for (int r = 0; r < 8; ++r)
        dst[(row0 + rg * 8 + r) * 64 + c] = acc[r];
}

// 4 projections fused: grid = 4 * 576; mat = bid&3 (adjacent bids share rows -> L2)
__global__ __launch_bounds__(256) void proj4_kernel(
    const float* __restrict__ state,
    const float* __restrict__ w0, const float* __restrict__ b0,
    const float* __restrict__ w1, const float* __restrict__ b1,
    const float* __restrict__ w2, const float* __restrict__ b2,
    const float* __restrict__ w3, const float* __restrict__ b3,
    float* __restrict__ o0, float* __restrict__ o1,
    float* __restrict__ o2, float* __restrict__ o3)
{
    __shared__ float sw[64 * 68];
    __shared__ float srow[32 * 64];
    __shared__ float sb[64];
    const int mat  = blockIdx.x & 3;
    const int row0 = (blockIdx.x >> 2) * 32;
    const float* w = (mat == 0) ? w0 : (mat == 1) ? w1 : (mat == 2) ? w2 : w3;
    const float* b = (mat == 0) ? b0 : (mat == 1) ? b1 : (mat == 2) ? b2 : b3;
    float* o       = (mat == 0) ? o0 : (mat == 1) ? o1 : (mat == 2) ? o2 : o3;
    proj_tile(state, w, b, o, row0, threadIdx.x, sw, srow, sb);
}

__global__ __launch_bounds__(256) void proj1_kernel(
    const float* __restrict__ src, const float* __restrict__ w,
    const float* __restrict__ b, float* __restrict__ dst)
{
    __shared__ float sw[64 * 68];
    __shared__ float srow[32 * 64];
    __shared__ float sb[64];
    proj_tile(src, w, b, dst, blockIdx.x * 32, threadIdx.x, sw, srow, sb);
}

// ---------------------------------------------------------------------------
// Scores: block per (bh, a); 384 threads = 96 y x 4 xg; writes
// P[bh, x, a, y] = exp(S/4). rk row lives in registers (per-lane y),
// lk rows broadcast from LDS. No max-subtract: |S| << 1 by construction.
// ---------------------------------------------------------------------------
__global__ __launch_bounds__(384) void scores_kernel(
    const float* __restrict__ lk, const float* __restrict__ rk,
    float* __restrict__ P)
{
    __shared__ float lks[96][16];
    const int bid = blockIdx.x;
    const int a  = bid % 96;
    const int bh = bid / 96;             // b*4 + h
    const int b  = bh >> 2, h = bh & 3;
    const int t  = threadIdx.x;
    const int base = b * ELEM_B + h * 16;

    {   // stage lk[x=0..95][16]: 384 threads = 96 rows x 4 quads
        const int row = t >> 2, q = t & 3;
        *(float4*)&lks[row][q * 4] =
            *(const float4*)(lk + base + (row * 96 + a) * 64 + q * 4);
    }
    const int y = t % 96, xg = t / 96;
    const float4* rkp = (const float4*)(rk + base + (a * 96 + y) * 64);
    const float4 r0 = rkp[0], r1 = rkp[1], r2 = rkp[2], r3 = rkp[3];
    __syncthreads();

    float* Pout = P + (size_t)(bh * 96) * 9216 + a * 96 + y;
#pragma unroll 4
    for (int i = 0; i < 24; ++i) {
        const int x = xg * 24 + i;
        const float4* lp = (const float4*)lks[x];
        const float4 l0 = lp[0], l1 = lp[1], l2 = lp[2], l3 = lp[3];
        float s = l0.x * r0.x;
        s = fmaf(l0.y, r0.y, s); s = fmaf(l0.z, r0.z, s); s = fmaf(l0.w, r0.w, s);
        s = fmaf(l1.x, r1.x, s); s = fmaf(l1.y, r1.y, s); s = fmaf(l1.z, r1.z, s);
        s = fmaf(l1.w, r1.w, s); s = fmaf(l2.x, r2.x, s); s = fmaf(l2.y, r2.y, s);
        s = fmaf(l2.z, r2.z, s); s = fmaf(l2.w, r2.w, s); s = fmaf(l3.x, r3.x, s);
        s = fmaf(l3.y, r3.y, s); s = fmaf(l3.z, r3.z, s); s = fmaf(l3.w, r3.w, s);
        Pout[(size_t)x * 9216] = __expf(s * 0.25f);
    }
}

// ---------------------------------------------------------------------------
// Contraction: O[x,y,d] = (sum_a P*lv*rv) / (sum_a P).
// Block per (bh, x-tile of 6, y-half of 48): 256 blocks, 384 threads
// (dq = t&3, y = (t>>2)%48, xg = (t>>2)/48; thread owns 3 x's).
// rv/P staged per 4-a tile with register prefetch; lv staged once.
// LDS = 36864 + 12288 + 4608 = 53760 B -> 2 blocks/CU.
// ---------------------------------------------------------------------------
__global__ __launch_bounds__(384) void contract_kernel(
    const float* __restrict__ lv, const float* __restrict__ rv,
    const float* __restrict__ P, float* __restrict__ xb)
{
    __shared__ float lvs[6][96][16];
    __shared__ float rvs[4][48][16];
    __shared__ float Ps[6][4][48];
    const int bid = blockIdx.x;
    const int xt = bid & 15, yh = (bid >> 4) & 1, bh = bid >> 5;
    const int b = bh >> 2, h = bh & 3;
    const int x0 = xt * 6, y0 = yh * 48;
    const int t = threadIdx.x;
    const int base = b * ELEM_B + h * 16;
    const size_t pbase = (size_t)(bh * 96) * 9216;

    // stage lv x-tile: 2304 float4 slots
#pragma unroll
    for (int j = 0; j < 6; ++j) {
        const int s = t + j * 384;
        const int xi = s / 384, rem = s % 384, aa = rem >> 2, q = rem & 3;
        *(float4*)&lvs[xi][aa][q * 4] =
            *(const float4*)(lv + base + ((x0 + xi) * 96 + aa) * 64 + q * 4);
    }

    const int dq = t & 3, q2 = t >> 2;
    const int y = q2 % 48, xg = q2 / 48;

    float4 acc[3]; float den[3];
#pragma unroll
    for (int xl = 0; xl < 3; ++xl) {
        acc[xl] = make_float4(0.f, 0.f, 0.f, 0.f);
        den[xl] = 0.f;
    }

    float4 rpre[2]; float ppre[3];
    // prefetch tile 0
#pragma unroll
    for (int j = 0; j < 2; ++j) {
        const int s = t + j * 384;
        const int ai = s / 192, rem = s % 192, yy = rem >> 2, qq = rem & 3;
        rpre[j] = *(const float4*)(rv + base + ((ai) * 96 + y0 + yy) * 64 + qq * 4);
    }
#pragma unroll
    for (int j = 0; j < 3; ++j) {
        const int s = t + j * 384;
        const int xi = s / 192, rem = s % 192, ai = rem / 48, yy = rem % 48;
        ppre[j] = P[pbase + (size_t)(x0 + xi) * 9216 + ai * 96 + y0 + yy];
    }

    for (int at = 0; at < 24; ++at) {
        __syncthreads();
        // commit prefetched tile (flat layouts match slot index exactly)
#pragma unroll
        for (int j = 0; j < 2; ++j) {
            const int s = t + j * 384;
            *(float4*)&((float*)rvs)[s * 4] = rpre[j];
        }
#pragma unroll
        for (int j = 0; j < 3; ++j) {
            const int s = t + j * 384;
            ((float*)Ps)[s] = ppre[j];
        }
        __syncthreads();
        if (at < 23) {
            const int a0n = (at + 1) * 4;
#pragma unroll
            for (int j = 0; j < 2; ++j) {
                const int s = t + j * 384;
                const int ai = s / 192, rem = s % 192, yy = rem >> 2, qq = rem & 3;
                rpre[j] = *(const float4*)(rv + base + ((a0n + ai) * 96 + y0 + yy) * 64 + qq * 4);
            }
#pragma unroll
            for (int j = 0; j < 3; ++j) {
                const int s = t + j * 384;
                const int xi = s / 192, rem = s % 192, ai = rem / 48, yy = rem % 48;
                ppre[j] = P[pbase + (size_t)(x0 + xi) * 9216 + (a0n + ai) * 96 + y0 + yy];
            }
        }
        const int abase = at * 4;
#pragma unroll
        for (int ai = 0; ai < 4; ++ai) {
            const float4 r4 = *(const float4*)&rvs[ai][y][dq * 4];
#pragma unroll
            for (int xl = 0; xl < 3; ++xl) {
                const int xi = xg * 3 + xl;
                const float p = Ps[xi][ai][y];
                const float4 l4 = *(const float4*)&lvs[xi][abase + ai][dq * 4];
                den[xl] += p;
                acc[xl].x = fmaf(p * l4.x, r4.x, acc[xl].x);
                acc[xl].y = fmaf(p * l4.y, r4.y, acc[xl].y);
                acc[xl].z = fmaf(p * l4.z, r4.z, acc[xl].z);
                acc[xl].w = fmaf(p * l4.w, r4.w, acc[xl].w);
            }
        }
    }

#pragma unroll
    for (int xl = 0; xl < 3; ++xl) {
        const int xi = xg * 3 + xl;
        const float inv = 1.0f / den[xl];
        float4 o;
        o.x = acc[xl].x * inv; o.y = acc[xl].y * inv;
        o.z = acc[xl].z * inv; o.w = acc[xl].w * inv;
        *(float4*)(xb + base + ((x0 + xi) * 96 + y0 + y) * 64 + dq * 4) = o;
    }
}

extern "C" void kernel_launch(void* const* d_in, const int* in_sizes, int n_in,
                              void* d_out, int out_size, void* d_ws, size_t ws_size,
                              hipStream_t stream)
{
    const float* state = (const float*)d_in[0];
    const float* w_lk  = (const float*)d_in[1];
    const float* b_lk  = (const float*)d_in[2];
    const float* w_rk  = (const float*)d_in[3];
    const float* b_rk  = (const float*)d_in[4];
    const float* w_lv  = (const float*)d_in[5];
    const float* b_lv  = (const float*)d_in[6];
    const float* w_rv  = (const float*)d_in[7];
    const float* b_rv  = (const float*)d_in[8];
    const float* w_out = (const float*)d_in[9];
    const float* b_out = (const float*)d_in[10];
    float* out = (float*)d_out;

    float* ws = (float*)d_ws;
    float* lk = ws;
    float* rk = ws + (size_t)TENS;
    float* lv = ws + (size_t)2 * TENS;
    float* rv = ws + (size_t)3 * TENS;
    float* xb = ws + (size_t)4 * TENS;
    float* P  = ws + (size_t)5 * TENS;   // 8*96*9216 floats = 28.3 MB

    proj4_kernel<<<4 * (T_ROWS / 32), 256, 0, stream>>>(
        state, w_lk, b_lk, w_rk, b_rk, w_lv, b_lv, w_rv, b_rv, lk, rk, lv, rv);
    scores_kernel<<<8 * 96, 384, 0, stream>>>(lk, rk, P);
    contract_kernel<<<256, 384, 0, stream>>>(lv, rv, P, xb);
    proj1_kernel<<<T_ROWS / 32, 256, 0, stream>>>(xb, w_out, b_out, out);
}